// Round 2
// 444.206 us; speedup vs baseline: 1.0027x; 1.0027x over previous
//
#include <hip/hip_runtime.h>
#include <stdint.h>

// Problem constants (from setup_inputs): B=4, L=4, N=2048, H=64, V=4
#define BB 4
#define LL 4
#define NN 2048
#define HH 64

typedef __attribute__((ext_vector_type(4))) float  f32x4;
typedef __attribute__((ext_vector_type(8))) short  short8;

static __device__ __forceinline__ uint16_t f2bf(float f) {
    uint32_t u = __float_as_uint(f);
    u += 0x7FFFu + ((u >> 16) & 1u);   // round-to-nearest-even (finite inputs only)
    return (uint16_t)(u >> 16);
}

// ---------------------------------------------------------------------------
// Kernel 1 (unchanged): fused fc + LayerNorm + tanh + projection through
// M = a@W. Writes base = x + 0.2*(h@M0) to d_out (fp32) and
// zT[b][l][e][m] (bf16, B-fragment-friendly transposed layout) for l=1..4.
// Grid: 256 blocks x 256 threads; each wave handles 8 consecutive rows.
// ---------------------------------------------------------------------------
__global__ __launch_bounds__(256) void prep_kernel(
    const float* __restrict__ x, const float* __restrict__ feat,
    const float* __restrict__ fc_w, const float* __restrict__ fc_b,
    const float* __restrict__ ln_g, const float* __restrict__ ln_b,
    const float* __restrict__ W, const float* __restrict__ a,
    float* __restrict__ out, uint16_t* __restrict__ zT)
{
    __shared__ float    sW[64 * 67];        // fc_w staged, pad 66->67 (bank spread)
    __shared__ uint16_t sM[5 * 64 * 64];    // M[l][d][e] in bf16 (40 KB)

    const int tid = threadIdx.x;

    for (int i = tid; i < 64 * 66; i += 256) {
        int d = i / 66, k = i - d * 66;
        sW[d * 67 + k] = fc_w[i];
    }
    for (int i = tid; i < 5 * 64 * 64; i += 256) {
        int l = i >> 12;
        int d = (i >> 6) & 63;
        int e = i & 63;
        const float* wp = W + (size_t)(d * 4) * 64 + e;
        float acc = a[l * 4 + 0] * wp[0]   + a[l * 4 + 1] * wp[64]
                  + a[l * 4 + 2] * wp[128] + a[l * 4 + 3] * wp[192];
        sM[i] = f2bf(acc);
    }
    __syncthreads();

    const int wave = tid >> 6, lane = tid & 63;
    const int row0 = blockIdx.x * 32 + wave * 8;   // global row in [0, 8192)
    const int b    = row0 >> 11;                   // / 2048
    const int m0   = row0 & 2047;                  // row within batch

    const float fcb = fc_b[lane], lng = ln_g[lane], lnb = ln_b[lane];

    float xv[8], hv[8];
#pragma unroll
    for (int r = 0; r < 8; r++) {
        const int row = row0 + r;
        xv[r] = x[(size_t)row * 64 + lane];
        const float f0 = feat[row * 2 + 0];
        const float f1 = feat[row * 2 + 1];
        float acc = fcb;
#pragma unroll
        for (int k = 0; k < 64; k++)
            acc += __shfl(xv[r], k) * sW[lane * 67 + k];
        acc += f0 * sW[lane * 67 + 64] + f1 * sW[lane * 67 + 65];
        // LayerNorm over the 64 lanes
        float s = acc, s2 = acc * acc;
#pragma unroll
        for (int off = 32; off > 0; off >>= 1) {
            s  += __shfl_xor(s,  off);
            s2 += __shfl_xor(s2, off);
        }
        const float mean = s * (1.0f / 64.0f);
        const float var  = s2 * (1.0f / 64.0f) - mean * mean;
        const float y = (acc - mean) * rsqrtf(var + 1e-5f) * lng + lnb;
        hv[r] = tanhf(y);
    }

    // z[l][r][e=lane] = sum_d h[r][d] * M[l][d][e]
    float accz[5][8];
#pragma unroll
    for (int l = 0; l < 5; l++)
#pragma unroll
        for (int r = 0; r < 8; r++) accz[l][r] = 0.0f;

    for (int d = 0; d < 64; d++) {
        float hb[8];
#pragma unroll
        for (int r = 0; r < 8; r++) hb[r] = __shfl(hv[r], d);
#pragma unroll
        for (int l = 0; l < 5; l++) {
            const float mv =
                __uint_as_float(((uint32_t)sM[(l << 12) + (d << 6) + lane]) << 16);
#pragma unroll
            for (int r = 0; r < 8; r++) accz[l][r] += hb[r] * mv;
        }
    }

    // base = x + 0.2 * (h @ M0)
#pragma unroll
    for (int r = 0; r < 8; r++)
        out[(size_t)(row0 + r) * 64 + lane] = xv[r] + 0.2f * accz[0][r];

    // zT[b][l-1][e=lane][m0..m0+7]  (bf16, 16B per lane)
#pragma unroll
    for (int l = 1; l < 5; l++) {
        uint32_t w0 = (uint32_t)f2bf(accz[l][0]) | ((uint32_t)f2bf(accz[l][1]) << 16);
        uint32_t w1 = (uint32_t)f2bf(accz[l][2]) | ((uint32_t)f2bf(accz[l][3]) << 16);
        uint32_t w2 = (uint32_t)f2bf(accz[l][4]) | ((uint32_t)f2bf(accz[l][5]) << 16);
        uint32_t w3 = (uint32_t)f2bf(accz[l][6]) | ((uint32_t)f2bf(accz[l][7]) << 16);
        uint4* dst = (uint4*)(zT + (((size_t)(b * 4 + (l - 1)) * 64 + lane) * 2048 + m0));
        *dst = make_uint4(w0, w1, w2, w3);
    }
}

// ---------------------------------------------------------------------------
// Kernel 2 (restructured): out[b,n,e] += 0.2 * sum_l sum_m adj[b,l,n,m]*z[l][m][e]
// Grid: 4(b) * 64(row-tile of 32) = 256 blocks x 256 threads (4 waves).
// Wave w owns adjacency label l=w over the FULL K=2048 (no K-split).
// Cross-label reduction in LDS, then vectorized plain RMW store — NO atomics.
// adj read straight from global (fp32 -> bf16 in regs), zT read from L2.
// ---------------------------------------------------------------------------
__global__ __launch_bounds__(256) void gemm_kernel(
    const float* __restrict__ adj, const uint16_t* __restrict__ zT,
    float* __restrict__ out)
{
    __shared__ float sAcc[4][32 * 64];   // 32 KB: per-wave 32x64 fp32 tile

    const int blk = blockIdx.x;
    const int rt  = blk & 63;            // row-tile
    const int b   = blk >> 6;            // batch

    const int wave = threadIdx.x >> 6;   // adjacency label l = wave (0..3)
    const int lane = threadIdx.x & 63;
    const int q    = lane >> 4;          // k-quad
    const int mr   = lane & 15;          // row (A) / col (B,C) within 16

    const int n0 = rt * 32;

    const float* adjBase = adj + ((size_t)(b * 4 + wave) * 2048) * 2048;
    const float* aRow0 = adjBase + (size_t)(n0 + mr) * 2048 + q * 8;
    const float* aRow1 = aRow0 + (size_t)16 * 2048;
    const uint16_t* zCol =
        zT + ((size_t)(b * 4 + wave) * 64 + mr) * 2048 + q * 8;

    f32x4 acc[2][4];
#pragma unroll
    for (int i = 0; i < 2; i++)
#pragma unroll
        for (int j = 0; j < 4; j++) acc[i][j] = (f32x4){0.f, 0.f, 0.f, 0.f};

    f32x4  af[2][2][2];   // [buf][row-frag][half]
    short8 bq[2][4];      // [buf][e-tile]

#define LOADSTEP(pp, s) do {                                                  \
        const float* _a0 = aRow0 + (s) * 32;                                  \
        const float* _a1 = aRow1 + (s) * 32;                                  \
        af[pp][0][0] = *(const f32x4*)(_a0);                                  \
        af[pp][0][1] = *(const f32x4*)(_a0 + 4);                              \
        af[pp][1][0] = *(const f32x4*)(_a1);                                  \
        af[pp][1][1] = *(const f32x4*)(_a1 + 4);                              \
        const uint16_t* _z = zCol + (s) * 32;                                 \
        bq[pp][0] = *(const short8*)(_z);                                     \
        bq[pp][1] = *(const short8*)(_z + 16 * 2048);                         \
        bq[pp][2] = *(const short8*)(_z + 32 * 2048);                         \
        bq[pp][3] = *(const short8*)(_z + 48 * 2048);                         \
    } while (0)

#define COMPUTE(pp) do {                                                      \
        short8 _fa0, _fa1;                                                    \
        _Pragma("unroll")                                                     \
        for (int j = 0; j < 4; j++) {                                         \
            _fa0[j]     = (short)f2bf(af[pp][0][0][j]);                       \
            _fa0[j + 4] = (short)f2bf(af[pp][0][1][j]);                       \
            _fa1[j]     = (short)f2bf(af[pp][1][0][j]);                       \
            _fa1[j + 4] = (short)f2bf(af[pp][1][1][j]);                       \
        }                                                                     \
        _Pragma("unroll")                                                     \
        for (int et = 0; et < 4; et++) {                                      \
            acc[0][et] = __builtin_amdgcn_mfma_f32_16x16x32_bf16(             \
                _fa0, bq[pp][et], acc[0][et], 0, 0, 0);                       \
            acc[1][et] = __builtin_amdgcn_mfma_f32_16x16x32_bf16(             \
                _fa1, bq[pp][et], acc[1][et], 0, 0, 0);                       \
        }                                                                     \
    } while (0)

    // Full K = 2048 -> 64 steps of 32, depth-1 double buffer (proven loop).
    LOADSTEP(0, 0);
    for (int s = 0; s < 62; s += 2) {
        LOADSTEP(1, s + 1);
        COMPUTE(0);
        LOADSTEP(0, s + 2);
        COMPUTE(1);
    }
    LOADSTEP(1, 63);
    COMPUTE(0);
    COMPUTE(1);

#undef LOADSTEP
#undef COMPUTE

    // Stash per-wave tile. C layout: col = et*16 + mr, row = f*16 + q*4 + r.
#pragma unroll
    for (int f = 0; f < 2; f++)
#pragma unroll
        for (int et = 0; et < 4; et++)
#pragma unroll
            for (int r = 0; r < 4; r++)
                sAcc[wave][(f * 16 + q * 4 + r) * 64 + et * 16 + mr] =
                    acc[f][et][r];
    __syncthreads();

    // Reduce 4 labels and RMW out (base = x + 0.2*z0 written by prep_kernel).
    // 32x64 = 2048 floats; each of 256 threads owns 8 consecutive floats.
    const int t    = threadIdx.x;
    const int row  = t >> 3;             // 0..31
    const int col0 = (t & 7) * 8;        // 0,8,...,56
    const int lo   = row * 64 + col0;
    float* op = out + ((size_t)b * 2048 + n0 + row) * 64 + col0;
#pragma unroll
    for (int p = 0; p < 2; p++) {
        f32x4 s = *(const f32x4*)&sAcc[0][lo + p * 4];
        s = s + *(const f32x4*)&sAcc[1][lo + p * 4];
        s = s + *(const f32x4*)&sAcc[2][lo + p * 4];
        s = s + *(const f32x4*)&sAcc[3][lo + p * 4];
        f32x4 o = *(f32x4*)(op + p * 4);
        o = o + 0.2f * s;
        *(f32x4*)(op + p * 4) = o;
    }
}

extern "C" void kernel_launch(void* const* d_in, const int* in_sizes, int n_in,
                              void* d_out, int out_size, void* d_ws, size_t ws_size,
                              hipStream_t stream) {
    const float* x    = (const float*)d_in[0];
    const float* feat = (const float*)d_in[1];
    const float* adj  = (const float*)d_in[2];
    const float* fc_w = (const float*)d_in[3];
    const float* fc_b = (const float*)d_in[4];
    const float* ln_g = (const float*)d_in[5];
    const float* ln_b = (const float*)d_in[6];
    const float* W    = (const float*)d_in[7];
    const float* a    = (const float*)d_in[8];

    float*    out = (float*)d_out;
    uint16_t* zT  = (uint16_t*)d_ws;   // 4*4*64*2048 bf16 = 4 MB

    prep_kernel<<<256, 256, 0, stream>>>(x, feat, fc_w, fc_b, ln_g, ln_b,
                                         W, a, out, zT);
    gemm_kernel<<<256, 256, 0, stream>>>(adj, zT, out);
}

// Round 3
// 441.219 us; speedup vs baseline: 1.0095x; 1.0068x over previous
//
#include <hip/hip_runtime.h>
#include <stdint.h>

// Problem constants (from setup_inputs): B=4, L=4, N=2048, H=64, V=4
#define BB 4
#define LL 4
#define NN 2048
#define HH 64

typedef __attribute__((ext_vector_type(4))) float  f32x4;
typedef __attribute__((ext_vector_type(8))) short  short8;

static __device__ __forceinline__ uint16_t f2bf(float f) {
    uint32_t u = __float_as_uint(f);
    u += 0x7FFFu + ((u >> 16) & 1u);   // round-to-nearest-even (finite inputs only)
    return (uint16_t)(u >> 16);
}

// ---------------------------------------------------------------------------
// Kernel 1: fused fc + LayerNorm + tanh + projection through M = a@W.
// Writes base = x + 0.2*(h@M0) to d_out (fp32) and zT[b][l][e][m] (bf16,
// B-fragment-friendly transposed layout) for l=1..4 to d_ws.
// Change vs prev: W staged to LDS with coalesced f32x4 loads before the
// sM (= a@W in bf16) build — replaces 320 strided 4B global loads/thread.
// Grid: 256 blocks x 256 threads; each wave handles 8 consecutive rows.
// ---------------------------------------------------------------------------
__global__ __launch_bounds__(256) void prep_kernel(
    const float* __restrict__ x, const float* __restrict__ feat,
    const float* __restrict__ fc_w, const float* __restrict__ fc_b,
    const float* __restrict__ ln_g, const float* __restrict__ ln_b,
    const float* __restrict__ W, const float* __restrict__ a,
    float* __restrict__ out, uint16_t* __restrict__ zT)
{
    __shared__ float    sW[64 * 67];        // fc_w staged, pad 66->67 (bank spread)
    __shared__ uint16_t sM[5 * 64 * 64];    // M[l][d][e] in bf16 (40 KB)
    __shared__ float    sWt[64 * 4 * 64];   // W staged raw (64 KB)

    const int tid = threadIdx.x;

    // Stage fc_w and W (coalesced).
    for (int i = tid; i < 64 * 66; i += 256) {
        int d = i / 66, k = i - d * 66;
        sW[d * 67 + k] = fc_w[i];
    }
    for (int i = tid; i < 64 * 4 * 64 / 4; i += 256)
        ((f32x4*)sWt)[i] = ((const f32x4*)W)[i];
    __syncthreads();

    // Build M[l][d][e] = sum_v a[l][v] * W[d][v][e] in bf16 from LDS.
    for (int i = tid; i < 5 * 64 * 64; i += 256) {
        int l = i >> 12;
        int d = (i >> 6) & 63;
        int e = i & 63;
        const float* wp = sWt + d * 256 + e;
        float acc = a[l * 4 + 0] * wp[0]   + a[l * 4 + 1] * wp[64]
                  + a[l * 4 + 2] * wp[128] + a[l * 4 + 3] * wp[192];
        sM[i] = f2bf(acc);
    }
    __syncthreads();

    const int wave = tid >> 6, lane = tid & 63;
    const int row0 = blockIdx.x * 32 + wave * 8;   // global row in [0, 8192)
    const int b    = row0 >> 11;                   // / 2048
    const int m0   = row0 & 2047;                  // row within batch

    const float fcb = fc_b[lane], lng = ln_g[lane], lnb = ln_b[lane];

    float xv[8], hv[8];
#pragma unroll
    for (int r = 0; r < 8; r++) {
        const int row = row0 + r;
        xv[r] = x[(size_t)row * 64 + lane];
        const float f0 = feat[row * 2 + 0];
        const float f1 = feat[row * 2 + 1];
        float acc = fcb;
#pragma unroll
        for (int k = 0; k < 64; k++)
            acc += __shfl(xv[r], k) * sW[lane * 67 + k];
        acc += f0 * sW[lane * 67 + 64] + f1 * sW[lane * 67 + 65];
        // LayerNorm over the 64 lanes
        float s = acc, s2 = acc * acc;
#pragma unroll
        for (int off = 32; off > 0; off >>= 1) {
            s  += __shfl_xor(s,  off);
            s2 += __shfl_xor(s2, off);
        }
        const float mean = s * (1.0f / 64.0f);
        const float var  = s2 * (1.0f / 64.0f) - mean * mean;
        const float y = (acc - mean) * rsqrtf(var + 1e-5f) * lng + lnb;
        hv[r] = tanhf(y);
    }

    // z[l][r][e=lane] = sum_d h[r][d] * M[l][d][e]
    float accz[5][8];
#pragma unroll
    for (int l = 0; l < 5; l++)
#pragma unroll
        for (int r = 0; r < 8; r++) accz[l][r] = 0.0f;

    for (int d = 0; d < 64; d++) {
        float hb[8];
#pragma unroll
        for (int r = 0; r < 8; r++) hb[r] = __shfl(hv[r], d);
#pragma unroll
        for (int l = 0; l < 5; l++) {
            const float mv =
                __uint_as_float(((uint32_t)sM[(l << 12) + (d << 6) + lane]) << 16);
#pragma unroll
            for (int r = 0; r < 8; r++) accz[l][r] += hb[r] * mv;
        }
    }

    // base = x + 0.2 * (h @ M0)
#pragma unroll
    for (int r = 0; r < 8; r++)
        out[(size_t)(row0 + r) * 64 + lane] = xv[r] + 0.2f * accz[0][r];

    // zT[b][l-1][e=lane][m0..m0+7]  (bf16, 16B per lane)
#pragma unroll
    for (int l = 1; l < 5; l++) {
        uint32_t w0 = (uint32_t)f2bf(accz[l][0]) | ((uint32_t)f2bf(accz[l][1]) << 16);
        uint32_t w1 = (uint32_t)f2bf(accz[l][2]) | ((uint32_t)f2bf(accz[l][3]) << 16);
        uint32_t w2 = (uint32_t)f2bf(accz[l][4]) | ((uint32_t)f2bf(accz[l][5]) << 16);
        uint32_t w3 = (uint32_t)f2bf(accz[l][6]) | ((uint32_t)f2bf(accz[l][7]) << 16);
        uint4* dst = (uint4*)(zT + (((size_t)(b * 4 + (l - 1)) * 64 + lane) * 2048 + m0));
        *dst = make_uint4(w0, w1, w2, w3);
    }
}

// ---------------------------------------------------------------------------
// Kernel 2: out[b,n,e] += 0.2 * sum_l sum_m adj[b,l,n,m] * z[l][m][e]
// Grid: 4(b) * 64(row-tile of 32) = 256 blocks x 512 threads (8 waves).
// Wave w owns (label l = w&3, K-half kh = w>>2): 32 steps of K=32 each.
// 2 waves/SIMD (was 1) -> TLP hides HBM latency; serial chain halved.
// Cross-label/K reduction in LDS, vectorized plain RMW store — no atomics.
// XCD-chunked block swizzle (256 % 8 == 0, bijective) for zT L2 locality.
// ---------------------------------------------------------------------------
__global__ __launch_bounds__(512) void gemm_kernel(
    const float* __restrict__ adj, const uint16_t* __restrict__ zT,
    float* __restrict__ out)
{
    __shared__ float sAcc[8][32 * 64];   // 64 KB: per-wave 32x64 fp32 tile

    // XCD swizzle: consecutive hw blocks round-robin XCDs; remap so each
    // XCD gets a contiguous chunk (one batch's zT panels stay in its L2).
    const int blk = (blockIdx.x & 7) * 32 + (blockIdx.x >> 3);
    const int rt  = blk & 63;            // row-tile
    const int b   = blk >> 6;            // batch

    const int wave = threadIdx.x >> 6;
    const int l    = wave & 3;           // adjacency label
    const int kh   = wave >> 2;          // K-half (0,1)
    const int lane = threadIdx.x & 63;
    const int q    = lane >> 4;          // k-quad
    const int mr   = lane & 15;          // row (A) / col (B,C) within 16

    const int n0 = rt * 32;
    const int k0 = kh * 1024;

    const float* adjBase = adj + ((size_t)(b * 4 + l) * 2048) * 2048;
    const float* aRow0 = adjBase + (size_t)(n0 + mr) * 2048 + k0 + q * 8;
    const float* aRow1 = aRow0 + (size_t)16 * 2048;
    const uint16_t* zCol =
        zT + ((size_t)(b * 4 + l) * 64 + mr) * 2048 + k0 + q * 8;

    f32x4 acc[2][4];
#pragma unroll
    for (int i = 0; i < 2; i++)
#pragma unroll
        for (int j = 0; j < 4; j++) acc[i][j] = (f32x4){0.f, 0.f, 0.f, 0.f};

    f32x4  af[2][2][2];   // [buf][row-frag][half]
    short8 bq[2][4];      // [buf][e-tile]

#define LOADSTEP(pp, s) do {                                                  \
        const float* _a0 = aRow0 + (s) * 32;                                  \
        const float* _a1 = aRow1 + (s) * 32;                                  \
        af[pp][0][0] = *(const f32x4*)(_a0);                                  \
        af[pp][0][1] = *(const f32x4*)(_a0 + 4);                              \
        af[pp][1][0] = *(const f32x4*)(_a1);                                  \
        af[pp][1][1] = *(const f32x4*)(_a1 + 4);                              \
        const uint16_t* _z = zCol + (s) * 32;                                 \
        bq[pp][0] = *(const short8*)(_z);                                     \
        bq[pp][1] = *(const short8*)(_z + 16 * 2048);                         \
        bq[pp][2] = *(const short8*)(_z + 32 * 2048);                         \
        bq[pp][3] = *(const short8*)(_z + 48 * 2048);                         \
    } while (0)

#define COMPUTE(pp) do {                                                      \
        short8 _fa0, _fa1;                                                    \
        _Pragma("unroll")                                                     \
        for (int j = 0; j < 4; j++) {                                         \
            _fa0[j]     = (short)f2bf(af[pp][0][0][j]);                       \
            _fa0[j + 4] = (short)f2bf(af[pp][0][1][j]);                       \
            _fa1[j]     = (short)f2bf(af[pp][1][0][j]);                       \
            _fa1[j + 4] = (short)f2bf(af[pp][1][1][j]);                       \
        }                                                                     \
        _Pragma("unroll")                                                     \
        for (int et = 0; et < 4; et++) {                                      \
            acc[0][et] = __builtin_amdgcn_mfma_f32_16x16x32_bf16(             \
                _fa0, bq[pp][et], acc[0][et], 0, 0, 0);                       \
            acc[1][et] = __builtin_amdgcn_mfma_f32_16x16x32_bf16(             \
                _fa1, bq[pp][et], acc[1][et], 0, 0, 0);                       \
        }                                                                     \
    } while (0)

    // K-half = 1024 -> 32 steps of 32, depth-1 register double buffer.
    LOADSTEP(0, 0);
    for (int s = 0; s < 30; s += 2) {
        LOADSTEP(1, s + 1);
        COMPUTE(0);
        LOADSTEP(0, s + 2);
        COMPUTE(1);
    }
    LOADSTEP(1, 31);
    COMPUTE(0);
    COMPUTE(1);

#undef LOADSTEP
#undef COMPUTE

    // Stash per-wave tile. C layout: col = et*16 + mr, row = f*16 + q*4 + r.
#pragma unroll
    for (int f = 0; f < 2; f++)
#pragma unroll
        for (int et = 0; et < 4; et++)
#pragma unroll
            for (int r = 0; r < 4; r++)
                sAcc[wave][(f * 16 + q * 4 + r) * 64 + et * 16 + mr] =
                    acc[f][et][r];
    __syncthreads();

    // Reduce 8 slices (4 labels x 2 K-halves) and RMW out.
    // 32x64 = 2048 floats; each of 512 threads owns 4 consecutive floats.
    const int t    = threadIdx.x;
    const int row  = t >> 4;             // 0..31
    const int col0 = (t & 15) * 4;       // 0,4,...,60
    const int lo   = row * 64 + col0;
    float* op = out + ((size_t)b * 2048 + n0 + row) * 64 + col0;
    f32x4 s = *(const f32x4*)&sAcc[0][lo];
#pragma unroll
    for (int w = 1; w < 8; w++)
        s = s + *(const f32x4*)&sAcc[w][lo];
    f32x4 o = *(f32x4*)op;
    o = o + 0.2f * s;
    *(f32x4*)op = o;
}

extern "C" void kernel_launch(void* const* d_in, const int* in_sizes, int n_in,
                              void* d_out, int out_size, void* d_ws, size_t ws_size,
                              hipStream_t stream) {
    const float* x    = (const float*)d_in[0];
    const float* feat = (const float*)d_in[1];
    const float* adj  = (const float*)d_in[2];
    const float* fc_w = (const float*)d_in[3];
    const float* fc_b = (const float*)d_in[4];
    const float* ln_g = (const float*)d_in[5];
    const float* ln_b = (const float*)d_in[6];
    const float* W    = (const float*)d_in[7];
    const float* a    = (const float*)d_in[8];

    float*    out = (float*)d_out;
    uint16_t* zT  = (uint16_t*)d_ws;   // 4*4*64*2048 bf16 = 4 MB

    prep_kernel<<<256, 256, 0, stream>>>(x, feat, fc_w, fc_b, ln_g, ln_b,
                                         W, a, out, zT);
    gemm_kernel<<<256, 512, 0, stream>>>(adj, zT, out);
}